// Round 1
// baseline (681.668 us; speedup 1.0000x reference)
//
#include <hip/hip_runtime.h>
#include <stdint.h>
#include <stddef.h>

typedef __attribute__((ext_vector_type(8))) short short8;
typedef __attribute__((ext_vector_type(4))) short short4_t;
typedef __attribute__((ext_vector_type(4))) float float4_t;

#define DEV static __device__ __forceinline__

DEV short f2bf(float f) {
  unsigned u = __builtin_bit_cast(unsigned, f);
  u = (u + 0x7FFFu + ((u >> 16) & 1u)) >> 16;   // RNE
  return (short)(unsigned short)u;
}

DEV void load_lds16(const short* g, short* l) {
  __builtin_amdgcn_global_load_lds((const __attribute__((address_space(1))) void*)g,
                                   (__attribute__((address_space(3))) void*)l,
                                   16, 0, 0);
}

DEV float groupMax16(float v) {
  v = fmaxf(v, __shfl_xor(v, 1));
  v = fmaxf(v, __shfl_xor(v, 2));
  v = fmaxf(v, __shfl_xor(v, 4));
  v = fmaxf(v, __shfl_xor(v, 8));
  return v;
}
DEV float groupSum16(float v) {
  v += __shfl_xor(v, 1);
  v += __shfl_xor(v, 2);
  v += __shfl_xor(v, 4);
  v += __shfl_xor(v, 8);
  return v;
}

// ---------------------------------------------------------------------------
// Weight repack: src fp32 [batch][R][C] -> dst bf16 [batch][C][R]
// ---------------------------------------------------------------------------
__global__ __launch_bounds__(256) void transpose_cvt(const float* __restrict__ src,
                                                     short* __restrict__ dst,
                                                     int R, int C) {
  __shared__ float t[64][65];
  src += (size_t)blockIdx.z * R * C;
  dst += (size_t)blockIdx.z * R * C;
  const int tid = threadIdx.x;
  const int r0 = blockIdx.y * 64, c0 = blockIdx.x * 64;
#pragma unroll
  for (int i = 0; i < 16; i++) {
    int r = i * 4 + (tid >> 6);
    t[r][tid & 63] = src[(size_t)(r0 + r) * C + c0 + (tid & 63)];
  }
  __syncthreads();
#pragma unroll
  for (int i = 0; i < 16; i++) {
    int c = i * 4 + (tid >> 6);
    dst[(size_t)(c0 + c) * R + r0 + (tid & 63)] = f2bf(t[tid & 63][c]);
  }
}

// fp32 -> bf16 elementwise (vectorized)
__global__ __launch_bounds__(256) void cvt_bf16(const float* __restrict__ in,
                                                short* __restrict__ out, int n4) {
  int i = blockIdx.x * 256 + threadIdx.x;
  if (i < n4) {
    float4_t v = ((const float4_t*)in)[i];
    short4_t o;
    o.x = f2bf(v.x); o.y = f2bf(v.y); o.z = f2bf(v.z); o.w = f2bf(v.w);
    ((short4_t*)out)[i] = o;
  }
}

// ---------------------------------------------------------------------------
// GEMM: C[M][N] = A[M][K](bf16,row-major) * Bt[N][K](bf16)^T, fp32 accum.
// MODE 0: scatter to Q,K [B,H,S,64] and V^T [B,H,64,S] (+bias on V cols)
// MODE 1: scatter to Q [B,H,S,64]
// MODE 2: scatter to K [B,H,S,64], V^T [B,H,64,S] (+bias on V cols)
// MODE 3: bf16 row-major out, +bias, ReLU
// MODE 4: fp32 row-major out, +bias
// ---------------------------------------------------------------------------
struct GemmArgs {
  const short* A;
  const short* Bt;
  int M, N, K;
  float* outf;
  short* outb;
  short* Qo;
  short* Ko;
  short* Vt;
  const float* bias;
};

template <int MODE>
__global__ __launch_bounds__(256) void gemm_k(GemmArgs args) {
  constexpr int BM = 128, BN = 128, BK = 64;
  __shared__ short As[BM * BK];
  __shared__ short Bs[BN * BK];
  const int tid = threadIdx.x;
  const int lane = tid & 63;
  const int w = tid >> 6;
  const int wr = w >> 1, wc = w & 1;
  const int row0 = blockIdx.y * BM;
  const int col0 = blockIdx.x * BN;
  const int K = args.K;
  const short* Ab = args.A + (size_t)row0 * K;
  const short* Bb = args.Bt + (size_t)col0 * K;
  float4_t acc[4][4] = {};
  const int r = lane & 15, kg = lane >> 4;

  for (int k0 = 0; k0 < K; k0 += BK) {
#pragma unroll
    for (int i = 0; i < 4; i++) {
      int c = i * 256 + tid;
      load_lds16(Ab + (size_t)(c >> 3) * K + k0 + (c & 7) * 8, &As[c * 8]);
    }
#pragma unroll
    for (int i = 0; i < 4; i++) {
      int c = i * 256 + tid;
      load_lds16(Bb + (size_t)(c >> 3) * K + k0 + (c & 7) * 8, &Bs[c * 8]);
    }
    __syncthreads();
#pragma unroll
    for (int kk = 0; kk < BK; kk += 32) {
      short8 a[4], b[4];
#pragma unroll
      for (int m = 0; m < 4; m++)
        a[m] = *(const short8*)&As[(wr * 64 + m * 16 + r) * BK + kk + kg * 8];
#pragma unroll
      for (int n = 0; n < 4; n++)
        b[n] = *(const short8*)&Bs[(wc * 64 + n * 16 + r) * BK + kk + kg * 8];
#pragma unroll
      for (int m = 0; m < 4; m++)
#pragma unroll
        for (int n = 0; n < 4; n++)
          acc[m][n] = __builtin_amdgcn_mfma_f32_16x16x32_bf16(a[m], b[n], acc[m][n], 0, 0, 0);
    }
    __syncthreads();
  }

  // epilogue: C row = row0+wr*64+m*16+(lane>>4)*4+j, col = col0+wc*64+n*16+(lane&15)
#pragma unroll
  for (int m = 0; m < 4; m++) {
#pragma unroll
    for (int n = 0; n < 4; n++) {
#pragma unroll
      for (int j = 0; j < 4; j++) {
        int row = row0 + wr * 64 + m * 16 + kg * 4 + j;
        int col = col0 + wc * 64 + n * 16 + r;
        float v = acc[m][n][j];
        if constexpr (MODE == 0) {
          int sel = col >> 10, cc = col & 1023;
          int h = cc >> 6, e = cc & 63;
          int b_ = row >> 11, s = row & 2047;
          if (sel == 0)
            args.Qo[(((size_t)(b_ * 16 + h)) * 2048 + s) * 64 + e] = f2bf(v);
          else if (sel == 1)
            args.Ko[(((size_t)(b_ * 16 + h)) * 2048 + s) * 64 + e] = f2bf(v);
          else {
            v += args.bias[cc];
            args.Vt[(((size_t)(b_ * 16 + h)) * 64 + e) * 2048 + s] = f2bf(v);
          }
        } else if constexpr (MODE == 1) {
          int h = col >> 6, e = col & 63;
          int b_ = row >> 11, s = row & 2047;
          args.Qo[(((size_t)(b_ * 16 + h)) * 2048 + s) * 64 + e] = f2bf(v);
        } else if constexpr (MODE == 2) {
          int sel = col >> 10, cc = col & 1023;
          int h = cc >> 6, e = cc & 63;
          int b_ = row >> 11, s = row & 2047;
          if (sel == 0)
            args.Ko[(((size_t)(b_ * 16 + h)) * 2048 + s) * 64 + e] = f2bf(v);
          else {
            v += args.bias[cc];
            args.Vt[(((size_t)(b_ * 16 + h)) * 64 + e) * 2048 + s] = f2bf(v);
          }
        } else if constexpr (MODE == 3) {
          v += args.bias[col];
          v = v > 0.f ? v : 0.f;
          args.outb[(size_t)row * args.N + col] = f2bf(v);
        } else {
          v += args.bias[col];
          args.outf[(size_t)row * args.N + col] = v;
        }
      }
    }
  }
}

// ---------------------------------------------------------------------------
// Flash attention. Q,K: [BH][S][64] bf16, Vt: [BH][64][S] bf16.
// Out: [B][S][H*64] fp32. 4 waves/block, 32 q-rows per wave, 32-key tiles.
// ---------------------------------------------------------------------------
template <bool CAUSAL>
__global__ __launch_bounds__(256) void attn_k(const short* __restrict__ Q,
                                              const short* __restrict__ Kq,
                                              const short* __restrict__ Vt,
                                              float* __restrict__ Out) {
  __shared__ short p_lds[4][32 * 40];  // pitch 40 keeps b128 reads 16B-aligned
  const int tid = threadIdx.x;
  const int lane = tid & 63;
  const int w = tid >> 6;
  const int bh = blockIdx.y;
  const int b_ = bh >> 4, h = bh & 15;
  const int q0 = blockIdx.x * 128 + w * 32;
  const int r = lane & 15, kg = lane >> 4;
  const size_t base = (size_t)bh * 2048 * 64;
  const short* Qb = Q + base;
  const short* Kb = Kq + base;
  const short* Vb = Vt + base;

  short8 q[2][2];
#pragma unroll
  for (int m = 0; m < 2; m++)
#pragma unroll
    for (int kc = 0; kc < 2; kc++)
      q[m][kc] = *(const short8*)&Qb[(size_t)(q0 + m * 16 + r) * 64 + kc * 32 + kg * 8];

  float4_t o[2][4] = {};
  float mrun[2][4], lrun[2][4];
#pragma unroll
  for (int m = 0; m < 2; m++)
#pragma unroll
    for (int j = 0; j < 4; j++) { mrun[m][j] = -1e30f; lrun[m][j] = 0.f; }

  const int NT = CAUSAL ? (q0 / 32 + 1) : 64;
  const float4_t zero4 = {0.f, 0.f, 0.f, 0.f};

  for (int kt = 0; kt < NT; kt++) {
    short8 kb[2][2];
#pragma unroll
    for (int n2 = 0; n2 < 2; n2++)
#pragma unroll
      for (int kc = 0; kc < 2; kc++)
        kb[n2][kc] = *(const short8*)&Kb[(size_t)(kt * 32 + n2 * 16 + r) * 64 + kc * 32 + kg * 8];

    float4_t sc[2][2];
#pragma unroll
    for (int m = 0; m < 2; m++)
#pragma unroll
      for (int n2 = 0; n2 < 2; n2++) {
        float4_t a0 = __builtin_amdgcn_mfma_f32_16x16x32_bf16(q[m][0], kb[n2][0], zero4, 0, 0, 0);
        sc[m][n2] = __builtin_amdgcn_mfma_f32_16x16x32_bf16(q[m][1], kb[n2][1], a0, 0, 0, 0);
      }

    float alpha[2][4];
    // wait for previous iteration's LDS reads before overwriting (per-wave)
    asm volatile("s_waitcnt lgkmcnt(0)" ::: "memory");
#pragma unroll
    for (int m = 0; m < 2; m++) {
#pragma unroll
      for (int j = 0; j < 4; j++) {
        float a0 = sc[m][0][j] * 0.125f;
        float a1 = sc[m][1][j] * 0.125f;
        if (CAUSAL && kt == NT - 1) {
          int rr = q0 + m * 16 + kg * 4 + j;
          if (kt * 32 + r > rr) a0 = -1e30f;
          if (kt * 32 + 16 + r > rr) a1 = -1e30f;
        }
        float tm = groupMax16(fmaxf(a0, a1));
        float mnew = fmaxf(mrun[m][j], tm);
        float al = __expf(mrun[m][j] - mnew);
        float p0 = __expf(a0 - mnew);
        float p1 = __expf(a1 - mnew);
        float rs = groupSum16(p0 + p1);
        lrun[m][j] = lrun[m][j] * al + rs;
        mrun[m][j] = mnew;
        alpha[m][j] = al;
        int prow = m * 16 + kg * 4 + j;
        p_lds[w][prow * 40 + r] = f2bf(p0);
        p_lds[w][prow * 40 + 16 + r] = f2bf(p1);
      }
    }
    asm volatile("s_waitcnt lgkmcnt(0)" ::: "memory");
    __builtin_amdgcn_sched_barrier(0);

    short8 pa[2];
    pa[0] = *(const short8*)&p_lds[w][(r)*40 + kg * 8];
    pa[1] = *(const short8*)&p_lds[w][(16 + r) * 40 + kg * 8];

#pragma unroll
    for (int m = 0; m < 2; m++)
#pragma unroll
      for (int n = 0; n < 4; n++)
#pragma unroll
        for (int j = 0; j < 4; j++) o[m][n][j] *= alpha[m][j];

#pragma unroll
    for (int n = 0; n < 4; n++) {
      short8 vb = *(const short8*)&Vb[(size_t)(n * 16 + r) * 2048 + kt * 32 + kg * 8];
      o[0][n] = __builtin_amdgcn_mfma_f32_16x16x32_bf16(pa[0], vb, o[0][n], 0, 0, 0);
      o[1][n] = __builtin_amdgcn_mfma_f32_16x16x32_bf16(pa[1], vb, o[1][n], 0, 0, 0);
    }
  }

#pragma unroll
  for (int m = 0; m < 2; m++) {
#pragma unroll
    for (int j = 0; j < 4; j++) {
      float inv = 1.0f / lrun[m][j];
      float* orow = Out + ((size_t)b_ * 2048 + q0 + m * 16 + kg * 4 + j) * 1024 + h * 64;
#pragma unroll
      for (int n = 0; n < 4; n++) orow[n * 16 + r] = o[m][n][j] * inv;
    }
  }
}

// ---------------------------------------------------------------------------
// out = LayerNorm(X + Y) * g + be ; fp32 out (+optional bf16 copy). One row
// (1024 elems) per 256-thread block. Safe in-place (outf may alias X).
// ---------------------------------------------------------------------------
__global__ __launch_bounds__(256) void add_ln_k(const float* __restrict__ X,
                                                const float* __restrict__ Y,
                                                const float* __restrict__ g,
                                                const float* __restrict__ be,
                                                float* __restrict__ outf,
                                                short* __restrict__ outb) {
  __shared__ float red[8];
  const int row = blockIdx.x;
  const int t = threadIdx.x;
  const int lane = t & 63, w = t >> 6;
  float4_t v = ((const float4_t*)(X + (size_t)row * 1024))[t];
  float4_t u = ((const float4_t*)(Y + (size_t)row * 1024))[t];
  v.x += u.x; v.y += u.y; v.z += u.z; v.w += u.w;
  float s = v.x + v.y + v.z + v.w;
#pragma unroll
  for (int off = 32; off >= 1; off >>= 1) s += __shfl_xor(s, off);
  if (lane == 0) red[w] = s;
  __syncthreads();
  float mean = (red[0] + red[1] + red[2] + red[3]) * (1.f / 1024.f);
  float dx = v.x - mean, dy = v.y - mean, dz = v.z - mean, dw = v.w - mean;
  float q2 = dx * dx + dy * dy + dz * dz + dw * dw;
#pragma unroll
  for (int off = 32; off >= 1; off >>= 1) q2 += __shfl_xor(q2, off);
  if (lane == 0) red[4 + w] = q2;
  __syncthreads();
  float var = (red[4] + red[5] + red[6] + red[7]) * (1.f / 1024.f);
  float rs = rsqrtf(var + 1e-5f);
  float4_t gg = ((const float4_t*)g)[t];
  float4_t bb = ((const float4_t*)be)[t];
  float4_t o;
  o.x = dx * rs * gg.x + bb.x;
  o.y = dy * rs * gg.y + bb.y;
  o.z = dz * rs * gg.z + bb.z;
  o.w = dw * rs * gg.w + bb.w;
  ((float4_t*)(outf + (size_t)row * 1024))[t] = o;
  if (outb != nullptr) {
    short4_t ob;
    ob.x = f2bf(o.x); ob.y = f2bf(o.y); ob.z = f2bf(o.z); ob.w = f2bf(o.w);
    ((short4_t*)(outb + (size_t)row * 1024))[t] = ob;
  }
}

// ---------------------------------------------------------------------------
extern "C" void kernel_launch(void* const* d_in, const int* in_sizes, int n_in,
                              void* d_out, int out_size, void* d_ws, size_t ws_size,
                              hipStream_t stream) {
  (void)in_sizes; (void)n_in; (void)out_size; (void)ws_size;
  const float* x_in = (const float*)d_in[0];
  const float* enc  = (const float*)d_in[1];
  const float* Wq1  = (const float*)d_in[2];
  const float* Wk1  = (const float*)d_in[3];
  const float* Wv1  = (const float*)d_in[4];
  const float* bv1  = (const float*)d_in[5];
  const float* Wq2  = (const float*)d_in[6];
  const float* Wk2  = (const float*)d_in[7];
  const float* Wv2  = (const float*)d_in[8];
  const float* bv2  = (const float*)d_in[9];
  const float* g1   = (const float*)d_in[10];
  const float* be1  = (const float*)d_in[11];
  const float* g2   = (const float*)d_in[12];
  const float* be2  = (const float*)d_in[13];
  const float* g3   = (const float*)d_in[14];
  const float* be3  = (const float*)d_in[15];
  const float* Wf1  = (const float*)d_in[16];
  const float* bf1  = (const float*)d_in[17];
  const float* Wf2  = (const float*)d_in[18];
  const float* bf2  = (const float*)d_in[19];
  float* out = (float*)d_out;

  char* ws = (char*)d_ws;
  size_t off = 0;
  auto alloc = [&](size_t bytes) -> void* {
    void* p = ws + off;
    off += (bytes + 255) & ~(size_t)255;
    return p;
  };
  short* wqkv1t = (short*)alloc((size_t)3072 * 1024 * 2);
  short* wq2t   = (short*)alloc((size_t)1024 * 1024 * 2);
  short* wkv2t  = (short*)alloc((size_t)2048 * 1024 * 2);
  short* wf1t   = (short*)alloc((size_t)4096 * 1024 * 2);
  short* wf2t   = (short*)alloc((size_t)1024 * 4096 * 2);
  short* act_bf = (short*)alloc((size_t)4096 * 1024 * 2);
  short* enc_bf = (short*)alloc((size_t)4096 * 1024 * 2);
  short* Qb     = (short*)alloc((size_t)4096 * 1024 * 2);
  short* Kb     = (short*)alloc((size_t)4096 * 1024 * 2);
  short* Vtb    = (short*)alloc((size_t)4096 * 1024 * 2);
  float* tmp_f  = (float*)alloc((size_t)4096 * 1024 * 4);
  float* xbuf   = (float*)alloc((size_t)4096 * 1024 * 4);
  short* h_bf   = (short*)alloc((size_t)4096 * 4096 * 2);

  dim3 blk(256);
  // weight repacks -> bf16 [N][K]
  transpose_cvt<<<dim3(1, 16, 16), blk, 0, stream>>>(Wq1, wqkv1t, 1024, 64);
  transpose_cvt<<<dim3(1, 16, 16), blk, 0, stream>>>(Wk1, wqkv1t + 1024 * 1024, 1024, 64);
  transpose_cvt<<<dim3(1, 16, 16), blk, 0, stream>>>(Wv1, wqkv1t + 2 * 1024 * 1024, 1024, 64);
  transpose_cvt<<<dim3(1, 16, 16), blk, 0, stream>>>(Wq2, wq2t, 1024, 64);
  transpose_cvt<<<dim3(1, 16, 16), blk, 0, stream>>>(Wk2, wkv2t, 1024, 64);
  transpose_cvt<<<dim3(1, 16, 16), blk, 0, stream>>>(Wv2, wkv2t + 1024 * 1024, 1024, 64);
  transpose_cvt<<<dim3(64, 16, 1), blk, 0, stream>>>(Wf1, wf1t, 1024, 4096);
  transpose_cvt<<<dim3(16, 64, 1), blk, 0, stream>>>(Wf2, wf2t, 4096, 1024);
  cvt_bf16<<<4096, blk, 0, stream>>>(x_in, act_bf, 1048576);
  cvt_bf16<<<4096, blk, 0, stream>>>(enc, enc_bf, 1048576);

  GemmArgs ga;
  // --- self-attention QKV projection ---
  ga.A = act_bf; ga.Bt = wqkv1t; ga.M = 4096; ga.N = 3072; ga.K = 1024;
  ga.outf = nullptr; ga.outb = nullptr; ga.Qo = Qb; ga.Ko = Kb; ga.Vt = Vtb; ga.bias = bv1;
  gemm_k<0><<<dim3(24, 32), blk, 0, stream>>>(ga);
  attn_k<true><<<dim3(16, 32), blk, 0, stream>>>(Qb, Kb, Vtb, tmp_f);
  add_ln_k<<<4096, blk, 0, stream>>>(tmp_f, x_in, g1, be1, xbuf, act_bf);

  // --- cross-attention ---
  ga.A = act_bf; ga.Bt = wq2t; ga.M = 4096; ga.N = 1024; ga.K = 1024;
  ga.Qo = Qb; ga.Ko = nullptr; ga.Vt = nullptr; ga.bias = nullptr;
  gemm_k<1><<<dim3(8, 32), blk, 0, stream>>>(ga);
  ga.A = enc_bf; ga.Bt = wkv2t; ga.M = 4096; ga.N = 2048; ga.K = 1024;
  ga.Qo = nullptr; ga.Ko = Kb; ga.Vt = Vtb; ga.bias = bv2;
  gemm_k<2><<<dim3(16, 32), blk, 0, stream>>>(ga);
  attn_k<false><<<dim3(16, 32), blk, 0, stream>>>(Qb, Kb, Vtb, tmp_f);
  add_ln_k<<<4096, blk, 0, stream>>>(xbuf, tmp_f, g2, be2, xbuf, act_bf);

  // --- FFN ---
  ga.A = act_bf; ga.Bt = wf1t; ga.M = 4096; ga.N = 4096; ga.K = 1024;
  ga.outb = h_bf; ga.bias = bf1; ga.Qo = nullptr; ga.Ko = nullptr; ga.Vt = nullptr;
  gemm_k<3><<<dim3(32, 32), blk, 0, stream>>>(ga);
  ga.A = h_bf; ga.Bt = wf2t; ga.M = 4096; ga.N = 1024; ga.K = 4096;
  ga.outf = tmp_f; ga.outb = nullptr; ga.bias = bf2;
  gemm_k<4><<<dim3(8, 32), blk, 0, stream>>>(ga);
  add_ln_k<<<4096, blk, 0, stream>>>(xbuf, tmp_f, g3, be3, out, nullptr);
}